// Round 7
// baseline (230.550 us; speedup 1.0000x reference)
//
#include <hip/hip_runtime.h>

#define E_EDGES 20000
#define D_DIM   128
#define HS      136           // W2h h-slices: 128 W2 + 1 bias + 7 zero (prefetch pad)

// prep grid layout
#define NBA 544               // W2/b2 -> fp16 identity cvt: 544*256*4 uint2 = HS*16384 fp16
#define NBH 313               // hidden slabs: ceil(20000/64) edge-blocks
#define NBC 320               // h_w fp32->fp16, grid-stride
#define NBD 250               // zero d_out (K-split atomic combine)

#define SLAB_B 21504          // per-eg hidden slab: 80 edges x 264B (132 h fp16 + pad)

typedef _Float16 f16x8 __attribute__((ext_vector_type(8)));
typedef _Float16 f16x2 __attribute__((ext_vector_type(2)));
typedef float    floatx4 __attribute__((ext_vector_type(4)));

union F8 { f16x8 v; f16x2 h2[4]; unsigned int u[4]; };

__device__ __forceinline__ unsigned short f32_to_f16(float f) {
    _Float16 h = (_Float16)f;
    return __builtin_bit_cast(unsigned short, h);
}

__device__ __forceinline__ void gload_lds16(const void* g, void* l) {
    __builtin_amdgcn_global_load_lds(
        (const __attribute__((address_space(1))) unsigned int*)g,
        (__attribute__((address_space(3))) unsigned int*)l, 16, 0, 0);
}

// ---------------------------------------------------------------------------
// Fused prep.
// Part A: W2h[h][c] = fp16(W2[h][c]) identity-layout cvt (h==128: b2; >128: 0).
// Part B: hidden fp16 slabs hslab[eg][edge 0..79][h 0..131] (edge stride 264B);
//         relu(ef@W1+b1) via LDS-staged W1; h=128 -> 1.0, 129..131 -> 0.
// Part C: h_w fp32 -> fp16 [e][j].
// Part D: zero d_out.
// ---------------------------------------------------------------------------
__global__ __launch_bounds__(256) void prep_all(
    const float* __restrict__ W2, const float* __restrict__ b2,
    const float* __restrict__ ef, const float* __restrict__ W1,
    const float* __restrict__ b1, const float* __restrict__ hw,
    unsigned short* __restrict__ w2h, char* __restrict__ hslab,
    unsigned short* __restrict__ hwb, float* __restrict__ outz)
{
    __shared__ __align__(16) char pmem[16384];
    const int bx = blockIdx.x;
    const int t  = threadIdx.x;

    if (bx < NBA) {
        // one uint2 (4 fp16) per thread-step; exactly 4 steps, no tail
        int u = bx * 256 + t;
        #pragma unroll
        for (int s = 0; s < 4; ++s, u += NBA * 256) {
            int g0  = u * 4;
            int h   = g0 >> 14;
            int rem = g0 & 16383;
            uint2 o = make_uint2(0u, 0u);
            if (h < 128) {
                float4 v = *(const float4*)(W2 + (size_t)h * 16384 + rem);
                o.x = f32_to_f16(v.x) | ((unsigned int)f32_to_f16(v.y) << 16);
                o.y = f32_to_f16(v.z) | ((unsigned int)f32_to_f16(v.w) << 16);
            } else if (h == 128) {
                float4 v = *(const float4*)(b2 + rem);
                o.x = f32_to_f16(v.x) | ((unsigned int)f32_to_f16(v.y) << 16);
                o.y = f32_to_f16(v.z) | ((unsigned int)f32_to_f16(v.w) << 16);
            }
            ((uint2*)w2h)[u] = o;
        }
    } else if (bx < NBA + NBH) {
        // LDS: W1s 16x128 f32 (8KB) | b1s 128 f32 (512B) | efs 64x17 f32 (4352B)
        float* W1s = (float*)pmem;
        float* b1s = (float*)(pmem + 8192);
        float (*efs)[17] = (float(*)[17])(pmem + 8704);
        const int b  = bx - NBA;
        const int e0 = b * 64;
        #pragma unroll
        for (int i = 0; i < 2; ++i)
            *(float4*)&W1s[(i * 256 + t) * 4] = ((const float4*)W1)[i * 256 + t];
        if (t < 32) *(float4*)&b1s[t * 4] = ((const float4*)b1)[t];
        {
            int e  = t >> 2;
            int k4 = (t & 3) * 4;
            int ge = e0 + e;
            float4 v = make_float4(0.f, 0.f, 0.f, 0.f);
            if (ge < E_EDGES) v = *(const float4*)(ef + (size_t)ge * 16 + k4);
            efs[e][k4 + 0] = v.x; efs[e][k4 + 1] = v.y;
            efs[e][k4 + 2] = v.z; efs[e][k4 + 3] = v.w;
        }
        __syncthreads();
        const int e  = t & 63;
        const int hg = t >> 6;                 // wave-uniform
        const int ge = e0 + e;
        const bool valid = ge < E_EDGES;
        const int eg = ge / 80;                // magic-mul
        const int re = ge - eg * 80;
        char* slab = hslab + (size_t)eg * SLAB_B + re * 264;
        float efr[16];
        #pragma unroll
        for (int k = 0; k < 16; ++k) efr[k] = efs[e][k];
        #pragma unroll 4
        for (int hi2 = 0; hi2 < 16; ++hi2) {
            const int h0 = hg * 32 + 2 * hi2;
            float2 bb = *(const float2*)&b1s[h0];
            float a0 = bb.x, a1 = bb.y;
            #pragma unroll
            for (int k = 0; k < 16; ++k) {
                float2 wv = *(const float2*)&W1s[k * 128 + h0];   // broadcast
                a0 += efr[k] * wv.x;
                a1 += efr[k] * wv.y;
            }
            unsigned int pk = (unsigned int)f32_to_f16(fmaxf(a0, 0.f))
                            | ((unsigned int)f32_to_f16(fmaxf(a1, 0.f)) << 16);
            if (valid) *(unsigned int*)(slab + h0 * 2) = pk;
        }
        if (hg == 0 && valid) {
            *(unsigned int*)(slab + 128 * 2) = 0x00003C00u;   // h=128: 1.0, h=129: 0
            *(unsigned int*)(slab + 130 * 2) = 0u;            // h=130,131: 0
        }
    } else if (bx < NBA + NBH + NBC) {
        int i0 = (bx - NBA - NBH) * 256 + t;
        for (int i = i0; i < (E_EDGES * D_DIM) / 4; i += NBC * 256) {
            const float4 v = ((const float4*)hw)[i];
            union { unsigned short u16[4]; uint2 u2; } o;
            o.u16[0] = f32_to_f16(v.x);
            o.u16[1] = f32_to_f16(v.y);
            o.u16[2] = f32_to_f16(v.z);
            o.u16[3] = f32_to_f16(v.w);
            ((uint2*)hwb)[i] = o.u2;
        }
    } else {
        int i0 = (bx - NBA - NBH - NBC) * 256 + t;
        float4* o4 = (float4*)outz;
        for (int i = i0; i < (E_EDGES * D_DIM) / 4; i += NBD * 256)
            o4[i] = make_float4(0.f, 0.f, 0.f, 0.f);
    }
}

// ---------------------------------------------------------------------------
// Main (Z-GEMM v2): 504 blocks x 256 threads. Block = 80 edges x 64 cols x 128 j.
// ch = (bx&7)>>2 (XCD-pinned -> 2.2MB B working set per XCD L2);
// eg = (bx>>3)*4 + (bx&3). Wave = j-QUARTER jq: 80e x 64c x 32j ->
// 20 MFMA/h/wave vs ~28 VALU instr/h/wave (no Z duplication: waves have
// disjoint j). B-frags read per-lane from NATURAL-layout fp16 W2h (16B
// contiguous per lane), register double-buffered (prefetch distance 2).
// Hidden slab (21KB) in LDS, broadcast ds_read_b64 per 4 h. 2 blocks/CU ->
// 8 waves/CU; regs ~172 (80 AGPR C + ~92 VGPR). j-quarters combined via
// fp32 atomicAdd onto zeroed d_out.
// ---------------------------------------------------------------------------
__global__ __launch_bounds__(256, 2)
void edge_main(const char* __restrict__ w2h, const char* __restrict__ hslab,
               const uint4* __restrict__ hwb, float* __restrict__ out) {
    __shared__ __align__(16) char slab[SLAB_B];
    const int bx  = blockIdx.x;
    const int ch  = (bx & 7) >> 2;
    const int eg  = (bx >> 3) * 4 + (bx & 3);
    if (eg >= 250) return;
    const int tid = threadIdx.x;
    const int jq  = tid >> 6;                 // j-quarter, 0..3
    const int l   = tid & 63;
    const int l4  = l >> 4;
    const int lm  = l & 15;
    const int e0  = eg * 80;

    // DMA hidden slab (80 edges x 132 h fp16) into LDS: 21 x 1KB
    {
        const char* src = hslab + (size_t)eg * SLAB_B;
        for (int i = jq; i < 21; i += 4)
            gload_lds16(src + i * 1024 + l * 16, slab + i * 1024);
    }

    // resident h_w A-source: hws[m] = hw[e0+16m+lm][32jq + 8*l4 .. +7]
    F8 hws[5];
    #pragma unroll
    for (int m = 0; m < 5; ++m)
        hws[m].v = ((const F8*)hwb)[(e0 + 16 * m + lm) * 16 + 4 * jq + l4].v;

    floatx4 C[5][4];
    #pragma unroll
    for (int m = 0; m < 5; ++m)
        #pragma unroll
        for (int nt = 0; nt < 4; ++nt)
            C[m][nt] = (floatx4){0.f, 0.f, 0.f, 0.f};

    __syncthreads();    // slab DMA drained; ONLY barrier

    // per-lane B base: elem (64ch+lm)*128 + 32jq + 8*l4 within an h-slice
    const char* bbase = w2h + (size_t)(((64 * ch + lm) << 7) + 32 * jq + 8 * l4) * 2;

    f16x8 B[2][4];
    auto loadB = [&](int h, f16x8 (&Bq)[4]) {
        const char* p = bbase + (size_t)h * 32768;
        #pragma unroll
        for (int nt = 0; nt < 4; ++nt)
            Bq[nt] = *(const f16x8*)(p + nt * 4096);   // col += 16 per n-tile
    };
    auto loadHid = [&](int q, uint2 (&hid)[5]) {       // h-quad q: h = 4q..4q+3
        #pragma unroll
        for (int m = 0; m < 5; ++m)
            hid[m] = *(const uint2*)(slab + (16 * m + lm) * 264 + q * 8);
    };
    auto doH = [&](int h, const uint2 (&hid)[5]) {
        const int hh = h & 3, p = h & 1;
        #pragma unroll
        for (int m = 0; m < 5; ++m) {
            unsigned int s   = (hh < 2) ? hid[m].x : hid[m].y;
            unsigned int sel = (hh & 1) ? 0x03020302u : 0x01000100u;
            f16x2 d = __builtin_bit_cast(f16x2, __builtin_amdgcn_perm(0u, s, sel));
            F8 a;
            #pragma unroll
            for (int i = 0; i < 4; ++i) a.h2[i] = hws[m].h2[i] * d;
            #pragma unroll
            for (int nt = 0; nt < 4; ++nt)
                C[m][nt] = __builtin_amdgcn_mfma_f32_16x16x32_f16(a.v, B[p][nt], C[m][nt], 0, 0, 0);
        }
        loadB(h + 2, B[p]);   // refill just-consumed buffer (h+2 <= 133 < 136)
    };

    loadB(0, B[0]);
    loadB(1, B[1]);
    uint2 hidA[5], hidB[5];
    loadHid(0, hidA);
    for (int q = 0; q < 32; q += 2) {
        loadHid(q + 1, hidB);
        doH(4*q + 0, hidA); doH(4*q + 1, hidA); doH(4*q + 2, hidA); doH(4*q + 3, hidA);
        loadHid(q + 2, hidA);                   // q+2 <= 32 ✓
        doH(4*q + 4, hidB); doH(4*q + 5, hidB); doH(4*q + 6, hidB); doH(4*q + 7, hidB);
    }
    doH(128, hidA); doH(129, hidA);             // bias row (scale 1.0)
    doH(130, hidA); doH(131, hidA);             // zero-scale pad rows

    // epilogue: C/D layout col = lane&15, row = 4*(lane>>4)+r ; combine j-quarters
    #pragma unroll
    for (int m = 0; m < 5; ++m)
        #pragma unroll
        for (int nt = 0; nt < 4; ++nt)
            #pragma unroll
            for (int r = 0; r < 4; ++r)
                atomicAdd(&out[(size_t)(e0 + 16 * m + 4 * l4 + r) * D_DIM
                               + 64 * ch + 16 * nt + lm], C[m][nt][r]);
}

// ---------------------------------------------------------------------------
extern "C" void kernel_launch(void* const* d_in, const int* in_sizes, int n_in,
                              void* d_out, int out_size, void* d_ws, size_t ws_size,
                              hipStream_t stream) {
    // inputs: h_v, h_w, edge_features, W1, b1, W2, b2 (fp32; h_v unused)
    const float* h_w = (const float*)d_in[1];
    const float* ef  = (const float*)d_in[2];
    const float* W1  = (const float*)d_in[3];
    const float* b1  = (const float*)d_in[4];
    const float* W2  = (const float*)d_in[5];
    const float* b2  = (const float*)d_in[6];
    float* out = (float*)d_out;

    char* ws = (char*)d_ws;
    unsigned short* w2h   = (unsigned short*)ws;                       // 136*32768 = 4,456,448 B
    char*           hslab = ws + 4456448;                              // 250*21504 = 5,376,000 B
    unsigned short* hwb   = (unsigned short*)(ws + 4456448 + 5376000); // 5,120,000 B
    // total ws use: 14,952,448 B

    hipLaunchKernelGGL(prep_all, dim3(NBA + NBH + NBC + NBD), dim3(256), 0, stream,
                       W2, b2, ef, W1, b1, h_w, w2h, hslab, hwb, out);
    hipLaunchKernelGGL(edge_main, dim3(504), dim3(256), 0, stream,
                       (const char*)w2h, hslab, (const uint4*)hwb, out);
}

// Round 8
// 177.300 us; speedup vs baseline: 1.3003x; 1.3003x over previous
//
#include <hip/hip_runtime.h>

#define E_EDGES 20000
#define D_DIM   128
#define HS      136           // bpf h-slices: 128 W2 + 1 bias + 7 zero (prefetch pad)

// prep grid layout
#define NBA 136               // W2/b2 repack: one h-slice per block
#define NBH 313               // hidden slabs: ceil(20000/64) edge-blocks
#define NBC 320               // h_w fp32->fp16, grid-stride
#define NBD 250               // zero d_out (j-split atomic combine)

#define SLAB_B 21504          // per-eg hidden slab: 80 edges x 264B (132 h fp16 + pad)

typedef _Float16 f16x8 __attribute__((ext_vector_type(8)));
typedef _Float16 f16x2 __attribute__((ext_vector_type(2)));
typedef float    floatx4 __attribute__((ext_vector_type(4)));

union F8 { f16x8 v; f16x2 h2[4]; unsigned int u[4]; };

__device__ __forceinline__ unsigned short f32_to_f16(float f) {
    _Float16 h = (_Float16)f;
    return __builtin_bit_cast(unsigned short, h);
}

__device__ __forceinline__ void gload_lds16(const void* g, void* l) {
    __builtin_amdgcn_global_load_lds(
        (const __attribute__((address_space(1))) unsigned int*)g,
        (__attribute__((address_space(3))) unsigned int*)l, 16, 0, 0);
}

// ---------------------------------------------------------------------------
// Fused prep.
// Part A: repack h-slice of W2 (h==128: b2; h>128: zeros) into fragment-major
//   fp16 bpf. cidx = ch*1024 + jq*256 + nt*64 + ll ; chunk elem j holds
//   B_h[k][col], col = 64ch+16nt+(ll&15), k = 32jq+8*(ll>>4)+j.
//   -> wave (ch,jq) reads 4 x 1KB CONTIGUOUS per h (fully coalesced).
// Part B: hidden fp16 slabs hslab[eg][edge 0..79][h 0..131] (stride 264B);
//   relu(ef@W1+b1) via LDS-staged W1; h=128 -> 1.0, 129..131 -> 0.
// Part C: h_w fp32 -> fp16 [e][j].
// Part D: zero d_out.
// ---------------------------------------------------------------------------
__global__ __launch_bounds__(256) void prep_all(
    const float* __restrict__ W2, const float* __restrict__ b2,
    const float* __restrict__ ef, const float* __restrict__ W1,
    const float* __restrict__ b1, const float* __restrict__ hw,
    uint4* __restrict__ bpf, char* __restrict__ hslab,
    unsigned short* __restrict__ hwb, float* __restrict__ outz)
{
    __shared__ __align__(16) char pmem[34816];
    const int bx = blockIdx.x;
    const int t  = threadIdx.x;

    if (bx < NBA) {
        const int h = bx;
        if (h < 129) {
            unsigned short* tile = (unsigned short*)pmem;   // [col][136]
            const float* src = (h < 128) ? (W2 + (size_t)h * (D_DIM * D_DIM)) : b2;
            #pragma unroll
            for (int r = 0; r < 16; ++r) {
                const float4 v = ((const float4*)src)[r * 256 + t];
                int c   = (r * 256 + t) * 4;
                int col = c >> 7;
                int k   = c & 127;
                unsigned int u0 = f32_to_f16(v.x) | ((unsigned int)f32_to_f16(v.y) << 16);
                unsigned int u1 = f32_to_f16(v.z) | ((unsigned int)f32_to_f16(v.w) << 16);
                *(uint2*)&tile[col * 136 + k] = make_uint2(u0, u1);
            }
            __syncthreads();
            #pragma unroll
            for (int r2 = 0; r2 < 8; ++r2) {
                int cidx = r2 * 256 + t;
                int ll = cidx & 63;
                int nt = (cidx >> 6) & 3;
                int jq = (cidx >> 8) & 3;
                int ch = (cidx >> 10) & 1;
                int col = 64 * ch + 16 * nt + (ll & 15);
                int k0  = 32 * jq + 8 * (ll >> 4);
                bpf[(size_t)h * 2048 + cidx] = *(const uint4*)&tile[col * 136 + k0];
            }
        } else {
            #pragma unroll
            for (int r2 = 0; r2 < 8; ++r2)
                bpf[(size_t)h * 2048 + r2 * 256 + t] = make_uint4(0, 0, 0, 0);
        }
    } else if (bx < NBA + NBH) {
        // LDS: W1s 16x128 f32 (8KB) | b1s 128 f32 (512B) | efs 64x17 f32 (4352B)
        float* W1s = (float*)pmem;
        float* b1s = (float*)(pmem + 8192);
        float (*efs)[17] = (float(*)[17])(pmem + 8704);
        const int b  = bx - NBA;
        const int e0 = b * 64;
        #pragma unroll
        for (int i = 0; i < 2; ++i)
            *(float4*)&W1s[(i * 256 + t) * 4] = ((const float4*)W1)[i * 256 + t];
        if (t < 32) *(float4*)&b1s[t * 4] = ((const float4*)b1)[t];
        {
            int e  = t >> 2;
            int k4 = (t & 3) * 4;
            int ge = e0 + e;
            float4 v = make_float4(0.f, 0.f, 0.f, 0.f);
            if (ge < E_EDGES) v = *(const float4*)(ef + (size_t)ge * 16 + k4);
            efs[e][k4 + 0] = v.x; efs[e][k4 + 1] = v.y;
            efs[e][k4 + 2] = v.z; efs[e][k4 + 3] = v.w;
        }
        __syncthreads();
        const int e  = t & 63;
        const int hg = t >> 6;                 // wave-uniform
        const int ge = e0 + e;
        const bool valid = ge < E_EDGES;
        const int eg = ge / 80;                // magic-mul
        const int re = ge - eg * 80;
        char* slab = hslab + (size_t)eg * SLAB_B + re * 264;
        float efr[16];
        #pragma unroll
        for (int k = 0; k < 16; ++k) efr[k] = efs[e][k];
        #pragma unroll 4
        for (int hi2 = 0; hi2 < 16; ++hi2) {
            const int h0 = hg * 32 + 2 * hi2;
            float2 bb = *(const float2*)&b1s[h0];
            float a0 = bb.x, a1 = bb.y;
            #pragma unroll
            for (int k = 0; k < 16; ++k) {
                float2 wv = *(const float2*)&W1s[k * 128 + h0];   // broadcast
                a0 += efr[k] * wv.x;
                a1 += efr[k] * wv.y;
            }
            unsigned int pk = (unsigned int)f32_to_f16(fmaxf(a0, 0.f))
                            | ((unsigned int)f32_to_f16(fmaxf(a1, 0.f)) << 16);
            if (valid) *(unsigned int*)(slab + h0 * 2) = pk;
        }
        if (hg == 0 && valid) {
            *(unsigned int*)(slab + 128 * 2) = 0x00003C00u;   // h=128: 1.0, h=129: 0
            *(unsigned int*)(slab + 130 * 2) = 0u;            // h=130,131: 0
        }
    } else if (bx < NBA + NBH + NBC) {
        int i0 = (bx - NBA - NBH) * 256 + t;
        for (int i = i0; i < (E_EDGES * D_DIM) / 4; i += NBC * 256) {
            const float4 v = ((const float4*)hw)[i];
            union { unsigned short u16[4]; uint2 u2; } o;
            o.u16[0] = f32_to_f16(v.x);
            o.u16[1] = f32_to_f16(v.y);
            o.u16[2] = f32_to_f16(v.z);
            o.u16[3] = f32_to_f16(v.w);
            ((uint2*)hwb)[i] = o.u2;
        }
    } else {
        int i0 = (bx - NBA - NBH - NBC) * 256 + t;
        float4* o4 = (float4*)outz;
        for (int i = i0; i < (E_EDGES * D_DIM) / 4; i += NBD * 256)
            o4[i] = make_float4(0.f, 0.f, 0.f, 0.f);
    }
}

// ---------------------------------------------------------------------------
// Main (Z-GEMM v3): 504 blocks x 256 threads. Block = 80 edges x 64 cols x 128 j.
// ch = (bx&7)>>2 (XCD-pinned -> 2.2MB B working set per XCD L2);
// eg = (bx>>3)*4 + (bx&3). Wave = j-quarter jq: 80e x 64c x 32j ->
// 20 MFMA/h/wave vs ~26 VALU/h/wave (disjoint j -> no Z duplication).
// B-frags from FRAGMENT-MAJOR bpf: 4 x 1KB contiguous loads per wave per h
// (fully coalesced), register double-buffered (prefetch distance 2).
// Hidden slab (21KB) in LDS, broadcast ds_read_b64 per 4 h. 2 blocks/CU.
// j-quarters combined via fp32 atomicAdd onto zeroed d_out.
// ---------------------------------------------------------------------------
__global__ __launch_bounds__(256, 2)
void edge_main(const uint4* __restrict__ bpf, const char* __restrict__ hslab,
               const uint4* __restrict__ hwb, float* __restrict__ out) {
    __shared__ __align__(16) char slab[SLAB_B];
    const int bx  = blockIdx.x;
    const int ch  = (bx & 7) >> 2;
    const int eg  = (bx >> 3) * 4 + (bx & 3);
    if (eg >= 250) return;
    const int tid = threadIdx.x;
    const int jq  = tid >> 6;                 // j-quarter, 0..3
    const int l   = tid & 63;
    const int l4  = l >> 4;
    const int lm  = l & 15;
    const int e0  = eg * 80;

    // DMA hidden slab (80 edges x 132 h fp16) into LDS: 21 x 1KB
    {
        const char* src = hslab + (size_t)eg * SLAB_B;
        for (int i = jq; i < 21; i += 4)
            gload_lds16(src + i * 1024 + l * 16, slab + i * 1024);
    }

    // resident h_w A-source: hws[m] = hw[e0+16m+lm][32jq + 8*l4 .. +7]
    F8 hws[5];
    #pragma unroll
    for (int m = 0; m < 5; ++m)
        hws[m].v = ((const F8*)hwb)[(e0 + 16 * m + lm) * 16 + 4 * jq + l4].v;

    floatx4 C[5][4];
    #pragma unroll
    for (int m = 0; m < 5; ++m)
        #pragma unroll
        for (int nt = 0; nt < 4; ++nt)
            C[m][nt] = (floatx4){0.f, 0.f, 0.f, 0.f};

    __syncthreads();    // slab DMA drained; ONLY barrier

    const f16x8* bpf8 = (const f16x8*)bpf;
    const int cbase = (ch * 4 + jq) * 256 + l;   // wave's 16B-chunk base within h-slice

    f16x8 B[2][4];
    auto loadB = [&](int h, f16x8 (&Bq)[4]) {
        const f16x8* p = bpf8 + (size_t)h * 2048 + cbase;
        #pragma unroll
        for (int nt = 0; nt < 4; ++nt)
            Bq[nt] = p[nt * 64];                 // 4 x 1KB contiguous
    };
    auto loadHid = [&](int q, uint2 (&hid)[5]) { // h-quad q: h = 4q..4q+3
        #pragma unroll
        for (int m = 0; m < 5; ++m)
            hid[m] = *(const uint2*)(slab + (16 * m + lm) * 264 + q * 8);
    };
    auto doH = [&](int h, const uint2 (&hid)[5]) {
        const int hh = h & 3, p = h & 1;
        #pragma unroll
        for (int m = 0; m < 5; ++m) {
            unsigned int s   = (hh < 2) ? hid[m].x : hid[m].y;
            unsigned int sel = (hh & 1) ? 0x03020302u : 0x01000100u;
            f16x2 d = __builtin_bit_cast(f16x2, __builtin_amdgcn_perm(0u, s, sel));
            F8 a;
            #pragma unroll
            for (int i = 0; i < 4; ++i) a.h2[i] = hws[m].h2[i] * d;
            #pragma unroll
            for (int nt = 0; nt < 4; ++nt)
                C[m][nt] = __builtin_amdgcn_mfma_f32_16x16x32_f16(a.v, B[p][nt], C[m][nt], 0, 0, 0);
        }
        loadB(h + 2, B[p]);   // refill just-consumed buffer (h+2 <= 133 < 136)
    };

    loadB(0, B[0]);
    loadB(1, B[1]);
    uint2 hidA[5], hidB[5];
    loadHid(0, hidA);
    for (int q = 0; q < 32; q += 2) {
        loadHid(q + 1, hidB);
        doH(4*q + 0, hidA); doH(4*q + 1, hidA); doH(4*q + 2, hidA); doH(4*q + 3, hidA);
        loadHid(q + 2, hidA);                   // q+2 <= 32 ✓
        doH(4*q + 4, hidB); doH(4*q + 5, hidB); doH(4*q + 6, hidB); doH(4*q + 7, hidB);
    }
    doH(128, hidA); doH(129, hidA);             // bias row (scale 1.0) + zero row
    doH(130, hidA); doH(131, hidA);             // zero-scale pad rows

    // epilogue: C/D layout col = lane&15, row = 4*(lane>>4)+r ; combine j-quarters
    #pragma unroll
    for (int m = 0; m < 5; ++m)
        #pragma unroll
        for (int nt = 0; nt < 4; ++nt)
            #pragma unroll
            for (int r = 0; r < 4; ++r)
                atomicAdd(&out[(size_t)(e0 + 16 * m + 4 * l4 + r) * D_DIM
                               + 64 * ch + 16 * nt + lm], C[m][nt][r]);
}

// ---------------------------------------------------------------------------
extern "C" void kernel_launch(void* const* d_in, const int* in_sizes, int n_in,
                              void* d_out, int out_size, void* d_ws, size_t ws_size,
                              hipStream_t stream) {
    // inputs: h_v, h_w, edge_features, W1, b1, W2, b2 (fp32; h_v unused)
    const float* h_w = (const float*)d_in[1];
    const float* ef  = (const float*)d_in[2];
    const float* W1  = (const float*)d_in[3];
    const float* b1  = (const float*)d_in[4];
    const float* W2  = (const float*)d_in[5];
    const float* b2  = (const float*)d_in[6];
    float* out = (float*)d_out;

    char* ws = (char*)d_ws;
    uint4*          bpf   = (uint4*)ws;                                // 136*32768 = 4,456,448 B
    char*           hslab = ws + 4456448;                              // 250*21504 = 5,376,000 B
    unsigned short* hwb   = (unsigned short*)(ws + 4456448 + 5376000); // 5,120,000 B
    // total ws use: 14,952,448 B

    hipLaunchKernelGGL(prep_all, dim3(NBA + NBH + NBC + NBD), dim3(256), 0, stream,
                       W2, b2, ef, W1, b1, h_w, bpf, hslab, hwb, out);
    hipLaunchKernelGGL(edge_main, dim3(504), dim3(256), 0, stream,
                       bpf, hslab, (const uint4*)hwb, out);
}

// Round 9
// 164.670 us; speedup vs baseline: 1.4001x; 1.0767x over previous
//
#include <hip/hip_runtime.h>

#define E_EDGES 20000
#define D_DIM   128
#define HS      136           // bpf h-slices: 128 W2 + 1 bias + 7 zero (prefetch pad)

// prep grid layout
#define NBA 136               // W2/b2 repack: one h-slice per block
#define NBH 313               // hidden slabs: ceil(20000/64) edge-blocks
#define NBC 320               // h_w fp32->fp16, grid-stride

#define SLAB_B 21504          // per-eg hidden slab: 80 edges x 264B (132 h fp16 + pad)

typedef _Float16 f16x8 __attribute__((ext_vector_type(8)));
typedef _Float16 f16x2 __attribute__((ext_vector_type(2)));
typedef float    floatx4 __attribute__((ext_vector_type(4)));

union F8 { f16x8 v; f16x2 h2[4]; unsigned int u[4]; };

__device__ __forceinline__ unsigned short f32_to_f16(float f) {
    _Float16 h = (_Float16)f;
    return __builtin_bit_cast(unsigned short, h);
}

__device__ __forceinline__ void gload_lds16(const void* g, void* l) {
    __builtin_amdgcn_global_load_lds(
        (const __attribute__((address_space(1))) unsigned int*)g,
        (__attribute__((address_space(3))) unsigned int*)l, 16, 0, 0);
}

// ---------------------------------------------------------------------------
// Fused prep.
// Part A: repack h-slice of W2 (h==128: b2; h>128: zeros) into fragment-major
//   fp16 bpf. cidx = ch*512 + jq*128 + nt*64 + ll (ch 2b, jq 2b, nt 1b);
//   chunk elem j: B_h[k][col], col = 32ch+16nt+(ll&15), k = 32jq+8*(ll>>4)+j.
//   -> wave (ch,jq) reads 2 x 1KB CONTIGUOUS per h (fully coalesced).
// Part B: hidden fp16 slabs hslab[eg][edge 0..79][h 0..131] (stride 264B);
//   relu(ef@W1+b1) via LDS-staged W1; h=128 -> 1.0, 129..131 -> 0.
// Part C: h_w fp32 -> fp16 [e][j].
// ---------------------------------------------------------------------------
__global__ __launch_bounds__(256) void prep_all(
    const float* __restrict__ W2, const float* __restrict__ b2,
    const float* __restrict__ ef, const float* __restrict__ W1,
    const float* __restrict__ b1, const float* __restrict__ hw,
    uint4* __restrict__ bpf, char* __restrict__ hslab,
    unsigned short* __restrict__ hwb)
{
    __shared__ __align__(16) char pmem[34816];
    const int bx = blockIdx.x;
    const int t  = threadIdx.x;

    if (bx < NBA) {
        const int h = bx;
        if (h < 129) {
            unsigned short* tile = (unsigned short*)pmem;   // [col][136]
            const float* src = (h < 128) ? (W2 + (size_t)h * (D_DIM * D_DIM)) : b2;
            #pragma unroll
            for (int r = 0; r < 16; ++r) {
                const float4 v = ((const float4*)src)[r * 256 + t];
                int c   = (r * 256 + t) * 4;
                int col = c >> 7;
                int k   = c & 127;
                unsigned int u0 = f32_to_f16(v.x) | ((unsigned int)f32_to_f16(v.y) << 16);
                unsigned int u1 = f32_to_f16(v.z) | ((unsigned int)f32_to_f16(v.w) << 16);
                *(uint2*)&tile[col * 136 + k] = make_uint2(u0, u1);
            }
            __syncthreads();
            #pragma unroll
            for (int r2 = 0; r2 < 8; ++r2) {
                int cidx = r2 * 256 + t;
                int ll = cidx & 63;
                int nt = (cidx >> 6) & 1;
                int jq = (cidx >> 7) & 3;
                int ch = (cidx >> 9) & 3;
                int col = 32 * ch + 16 * nt + (ll & 15);
                int k0  = 32 * jq + 8 * (ll >> 4);
                bpf[(size_t)h * 2048 + cidx] = *(const uint4*)&tile[col * 136 + k0];
            }
        } else {
            #pragma unroll
            for (int r2 = 0; r2 < 8; ++r2)
                bpf[(size_t)h * 2048 + r2 * 256 + t] = make_uint4(0, 0, 0, 0);
        }
    } else if (bx < NBA + NBH) {
        // LDS: W1s 16x128 f32 (8KB) | b1s 128 f32 (512B) | efs 64x17 f32 (4352B)
        float* W1s = (float*)pmem;
        float* b1s = (float*)(pmem + 8192);
        float (*efs)[17] = (float(*)[17])(pmem + 8704);
        const int b  = bx - NBA;
        const int e0 = b * 64;
        #pragma unroll
        for (int i = 0; i < 2; ++i)
            *(float4*)&W1s[(i * 256 + t) * 4] = ((const float4*)W1)[i * 256 + t];
        if (t < 32) *(float4*)&b1s[t * 4] = ((const float4*)b1)[t];
        {
            int e  = t >> 2;
            int k4 = (t & 3) * 4;
            int ge = e0 + e;
            float4 v = make_float4(0.f, 0.f, 0.f, 0.f);
            if (ge < E_EDGES) v = *(const float4*)(ef + (size_t)ge * 16 + k4);
            efs[e][k4 + 0] = v.x; efs[e][k4 + 1] = v.y;
            efs[e][k4 + 2] = v.z; efs[e][k4 + 3] = v.w;
        }
        __syncthreads();
        const int e  = t & 63;
        const int hg = t >> 6;                 // wave-uniform
        const int ge = e0 + e;
        const bool valid = ge < E_EDGES;
        const int eg = ge / 80;                // magic-mul
        const int re = ge - eg * 80;
        char* slab = hslab + (size_t)eg * SLAB_B + re * 264;
        float efr[16];
        #pragma unroll
        for (int k = 0; k < 16; ++k) efr[k] = efs[e][k];
        #pragma unroll 4
        for (int hi2 = 0; hi2 < 16; ++hi2) {
            const int h0 = hg * 32 + 2 * hi2;
            float2 bb = *(const float2*)&b1s[h0];
            float a0 = bb.x, a1 = bb.y;
            #pragma unroll
            for (int k = 0; k < 16; ++k) {
                float2 wv = *(const float2*)&W1s[k * 128 + h0];   // broadcast
                a0 += efr[k] * wv.x;
                a1 += efr[k] * wv.y;
            }
            unsigned int pk = (unsigned int)f32_to_f16(fmaxf(a0, 0.f))
                            | ((unsigned int)f32_to_f16(fmaxf(a1, 0.f)) << 16);
            if (valid) *(unsigned int*)(slab + h0 * 2) = pk;
        }
        if (hg == 0 && valid) {
            *(unsigned int*)(slab + 128 * 2) = 0x00003C00u;   // h=128: 1.0, h=129: 0
            *(unsigned int*)(slab + 130 * 2) = 0u;            // h=130,131: 0
        }
    } else {
        int i0 = (bx - NBA - NBH) * 256 + t;
        for (int i = i0; i < (E_EDGES * D_DIM) / 4; i += NBC * 256) {
            const float4 v = ((const float4*)hw)[i];
            union { unsigned short u16[4]; uint2 u2; } o;
            o.u16[0] = f32_to_f16(v.x);
            o.u16[1] = f32_to_f16(v.y);
            o.u16[2] = f32_to_f16(v.z);
            o.u16[3] = f32_to_f16(v.w);
            ((uint2*)hwb)[i] = o.u2;
        }
    }
}

// ---------------------------------------------------------------------------
// Main (Z-GEMM v4): 1000 blocks x 256 threads, NO dead blocks.
// Block = 80 edges x 32 cols x 128 j. ch = (bx&7)>>1 in [0,4) is XCD-pinned
// (1.08 MB B working set per XCD L2); eg = (bx>>3)*2 + (bx&1) in [0,250).
// Wave = j-quarter jq: 80e x 32c x 32j -> 10 MFMA/h/wave, ~27 VALU/h/wave
// (disjoint j -> no Z duplication). B-frags from fragment-major bpf:
// 2 x 1KB contiguous loads per wave per h, register dbuf (prefetch dist 2).
// Hidden slab (21KB) in LDS, broadcast ds_read_b64 per 4 h (single-buffer JIT).
// __launch_bounds__(256,4) -> 4 blocks/CU = 16 waves/CU = 4 waves/SIMD
// (regs ~75 arch + 40 acc = ~115 <= 128). Epilogue: jq partials reduced
// IN-BLOCK via LDS (reuse slab) -> plain coalesced stores, NO atomics.
// ---------------------------------------------------------------------------
__global__ __launch_bounds__(256, 4)
void edge_main(const uint4* __restrict__ bpf, const char* __restrict__ hslab,
               const uint4* __restrict__ hwb, float* __restrict__ out) {
    __shared__ __align__(16) char slab[SLAB_B];
    const int bx  = blockIdx.x;
    const int ch  = (bx & 7) >> 1;            // 0..3, constant per XCD
    const int eg  = (bx >> 3) * 2 + (bx & 1); // 0..249
    const int tid = threadIdx.x;
    const int jq  = tid >> 6;                 // j-quarter, 0..3
    const int l   = tid & 63;
    const int l4  = l >> 4;
    const int lm  = l & 15;
    const int e0  = eg * 80;

    // DMA hidden slab (80 edges x 132 h fp16) into LDS: 21 x 1KB
    {
        const char* src = hslab + (size_t)eg * SLAB_B;
        for (int i = jq; i < 21; i += 4)
            gload_lds16(src + i * 1024 + l * 16, slab + i * 1024);
    }

    // resident h_w A-source: hws[m] = hw[e0+16m+lm][32jq + 8*l4 .. +7]
    F8 hws[5];
    #pragma unroll
    for (int m = 0; m < 5; ++m)
        hws[m].v = ((const F8*)hwb)[(e0 + 16 * m + lm) * 16 + 4 * jq + l4].v;

    floatx4 C[5][2];
    #pragma unroll
    for (int m = 0; m < 5; ++m)
        #pragma unroll
        for (int nt = 0; nt < 2; ++nt)
            C[m][nt] = (floatx4){0.f, 0.f, 0.f, 0.f};

    __syncthreads();    // slab DMA drained; only barrier before epilogue

    const f16x8* bpf8 = (const f16x8*)bpf;
    const int cbase = ch * 512 + jq * 128 + l;   // wave's 16B-chunk base within h-slice

    f16x8 B[2][2];
    auto loadB = [&](int h, f16x8 (&Bq)[2]) {
        const f16x8* p = bpf8 + (size_t)h * 2048 + cbase;
        Bq[0] = p[0];
        Bq[1] = p[64];                            // 2 x 1KB contiguous
    };
    auto doH = [&](int h, const uint2 (&hid)[5]) {
        const int hh = h & 3, p = h & 1;
        #pragma unroll
        for (int m = 0; m < 5; ++m) {
            unsigned int s   = (hh < 2) ? hid[m].x : hid[m].y;
            unsigned int sel = (hh & 1) ? 0x03020302u : 0x01000100u;
            f16x2 d = __builtin_bit_cast(f16x2, __builtin_amdgcn_perm(0u, s, sel));
            F8 a;
            #pragma unroll
            for (int i = 0; i < 4; ++i) a.h2[i] = hws[m].h2[i] * d;
            C[m][0] = __builtin_amdgcn_mfma_f32_16x16x32_f16(a.v, B[p][0], C[m][0], 0, 0, 0);
            C[m][1] = __builtin_amdgcn_mfma_f32_16x16x32_f16(a.v, B[p][1], C[m][1], 0, 0, 0);
        }
        loadB(h + 2, B[p]);   // refill just-consumed buffer (h+2 <= 133 < 136)
    };

    loadB(0, B[0]);
    loadB(1, B[1]);
    for (int q = 0; q < 33; ++q) {            // h-quad q: h = 4q..4q+3; q=32 = bias+pads
        uint2 hid[5];
        #pragma unroll
        for (int m = 0; m < 5; ++m)           // broadcast ds_read_b64 (l4 ignored)
            hid[m] = *(const uint2*)(slab + (16 * m + lm) * 264 + q * 8);
        doH(4 * q + 0, hid);
        doH(4 * q + 1, hid);
        doH(4 * q + 2, hid);
        doH(4 * q + 3, hid);
    }

    // epilogue: reduce the 4 jq partials in-block via LDS (reuse slab), then
    // plain coalesced stores. C/D layout: col = lane&15, row = 4*(lane>>4)+r.
    float* red = (float*)slab;
    #pragma unroll 1
    for (int src = 1; src < 4; ++src) {
        __syncthreads();
        if (jq == src) {
            #pragma unroll
            for (int m = 0; m < 5; ++m)
                #pragma unroll
                for (int nt = 0; nt < 2; ++nt)
                    #pragma unroll
                    for (int r = 0; r < 4; ++r)
                        red[((m * 2 + nt) * 4 + r) * 64 + l] = C[m][nt][r];
        }
        __syncthreads();
        if (jq == 0) {
            #pragma unroll
            for (int m = 0; m < 5; ++m)
                #pragma unroll
                for (int nt = 0; nt < 2; ++nt)
                    #pragma unroll
                    for (int r = 0; r < 4; ++r)
                        C[m][nt][r] += red[((m * 2 + nt) * 4 + r) * 64 + l];
        }
    }
    if (jq == 0) {
        #pragma unroll
        for (int m = 0; m < 5; ++m)
            #pragma unroll
            for (int nt = 0; nt < 2; ++nt)
                #pragma unroll
                for (int r = 0; r < 4; ++r)
                    out[(size_t)(e0 + 16 * m + 4 * l4 + r) * D_DIM
                        + 32 * ch + 16 * nt + lm] = C[m][nt][r];
    }
}

// ---------------------------------------------------------------------------
extern "C" void kernel_launch(void* const* d_in, const int* in_sizes, int n_in,
                              void* d_out, int out_size, void* d_ws, size_t ws_size,
                              hipStream_t stream) {
    // inputs: h_v, h_w, edge_features, W1, b1, W2, b2 (fp32; h_v unused)
    const float* h_w = (const float*)d_in[1];
    const float* ef  = (const float*)d_in[2];
    const float* W1  = (const float*)d_in[3];
    const float* b1  = (const float*)d_in[4];
    const float* W2  = (const float*)d_in[5];
    const float* b2  = (const float*)d_in[6];
    float* out = (float*)d_out;

    char* ws = (char*)d_ws;
    uint4*          bpf   = (uint4*)ws;                                // 136*32768 = 4,456,448 B
    char*           hslab = ws + 4456448;                              // 250*21504 = 5,376,000 B
    unsigned short* hwb   = (unsigned short*)(ws + 4456448 + 5376000); // 5,120,000 B
    // total ws use: 14,952,448 B

    hipLaunchKernelGGL(prep_all, dim3(NBA + NBH + NBC), dim3(256), 0, stream,
                       W2, b2, ef, W1, b1, h_w, bpf, hslab, hwb);
    hipLaunchKernelGGL(edge_main, dim3(1000), dim3(256), 0, stream,
                       bpf, hslab, (const uint4*)hwb, out);
}